// Round 1
// baseline (2150.870 us; speedup 1.0000x reference)
//
#include <hip/hip_runtime.h>

// ---------------------------------------------------------------------------
// HopfieldPooling on MI355X (gfx950)
//   k = x@Wk^T  (split-bf16 MFMA GEMM, 3-term: hi*hi + lo*hi + hi*lo)
//   q0 = query@Wq^T (fp32)
//   3x Hopfield attention steps, flash-style online softmax_1 (split-bf16 MFMA)
//   out = (q@Wv^T)@Wproj^T + b  (fp32 vector)
// ---------------------------------------------------------------------------

typedef float  float4v  __attribute__((ext_vector_type(4)));
typedef short  short4v  __attribute__((ext_vector_type(4)));
typedef short  short8v  __attribute__((ext_vector_type(8)));
typedef short8v bf16x8;   // 8 bf16 (bit-pattern in shorts) = 4 VGPRs, MFMA A/B frag

__device__ __forceinline__ unsigned short f2bf_hi(float f){
  unsigned int u = __float_as_uint(f);
  u += 0x7fffu + ((u >> 16) & 1u);            // round-to-nearest-even
  return (unsigned short)(u >> 16);
}
__device__ __forceinline__ float bf2f(unsigned short h){
  return __uint_as_float(((unsigned int)h) << 16);
}

// ---------------------------------------------------------------------------
// Wk -> hi/lo bf16 preconversion (768x768)
// ---------------------------------------------------------------------------
__global__ __launch_bounds__(256)
void cvt_w_kernel(const float* __restrict__ w, unsigned short* __restrict__ wh,
                  unsigned short* __restrict__ wl){
  int idx = blockIdx.x*256 + threadIdx.x;     // 147456 float4s
  float4v v = ((const float4v*)w)[idx];
  short4v h4, l4;
  #pragma unroll
  for(int e=0;e<4;e++){
    unsigned short hh = f2bf_hi(v[e]);
    h4[e] = (short)hh;
    l4[e] = (short)f2bf_hi(v[e] - bf2f(hh));
  }
  ((short4v*)wh)[idx] = h4;
  ((short4v*)wl)[idx] = l4;
}

// ---------------------------------------------------------------------------
// q0[l][c] = sum_j query[l][j]*Wq[c][j]   (16x768, fp32)
// ---------------------------------------------------------------------------
__global__ __launch_bounds__(256)
void q0_kernel(const float* __restrict__ query, const float* __restrict__ wq,
               float* __restrict__ q0){
  int idx = blockIdx.x*256 + threadIdx.x;     // 12288
  int l = idx / 768, c = idx - l*768;
  const float* qr = query + l*768;
  const float* wr = wq + (size_t)c*768;
  float s = 0.f;
  for(int j=0;j<768;j+=4){
    float4v a  = *(const float4v*)(qr+j);
    float4v w4 = *(const float4v*)(wr+j);
    s += a[0]*w4[0]+a[1]*w4[1]+a[2]*w4[2]+a[3]*w4[3];
  }
  q0[idx] = s;
}

// ---------------------------------------------------------------------------
// k = x @ Wk^T : M=65536, N=768, K=768. 128x128 tile, BK=32, 4 waves,
// each wave 64x64 (4x4 MFMA 16x16x32 subtiles), 3 MFMA per subtile (split).
// x converted fp32->hi/lo on the fly; Wk preconverted.
// ---------------------------------------------------------------------------
__global__ __launch_bounds__(256, 2)
void gemm_k_kernel(const float* __restrict__ x, const unsigned short* __restrict__ wh,
                   const unsigned short* __restrict__ wl, float* __restrict__ kout){
  __shared__ unsigned short Ah[128*40], Al[128*40];   // stride 40 shorts (pad)
  __shared__ unsigned short Bh[128*48], Bl[128*48];   // stride 48 shorts (pad)
  const int tid  = threadIdx.x;
  const int bm   = blockIdx.x;   // 0..511
  const int bn   = blockIdx.y;   // 0..5
  const int wave = tid >> 6, lane = tid & 63, quad = lane >> 4, l16 = lane & 15;
  const int wm   = (wave >> 1)*64, wn = (wave & 1)*64;

  float4v acc[4][4];
  #pragma unroll
  for(int i=0;i<4;i++)
    #pragma unroll
    for(int j=0;j<4;j++) acc[i][j] = (float4v){0.f,0.f,0.f,0.f};

  const float* xA = x + (size_t)bm*128*768;
  const unsigned short* wBh = wh + (size_t)bn*128*768;
  const unsigned short* wBl = wl + (size_t)bn*128*768;

  for(int k0=0;k0<768;k0+=32){
    __syncthreads();
    // stage A (x tile 128x32), convert to hi/lo
    #pragma unroll
    for(int i=0;i<4;i++){
      int fi = tid + i*256;          // 0..1023
      int row = fi >> 3, c4 = fi & 7;
      float4v va = *(const float4v*)(xA + (size_t)row*768 + k0 + c4*4);
      short4v ha, la;
      #pragma unroll
      for(int e=0;e<4;e++){
        unsigned short hh = f2bf_hi(va[e]);
        ha[e] = (short)hh;
        la[e] = (short)f2bf_hi(va[e] - bf2f(hh));
      }
      *(short4v*)(Ah + row*40 + c4*4) = ha;
      *(short4v*)(Al + row*40 + c4*4) = la;
    }
    // stage B (Wk tile 128x32, already bf16 hi/lo)
    #pragma unroll
    for(int i=0;i<2;i++){
      int ci = tid + i*256;          // 0..511
      int row = ci >> 2, c16 = ci & 3;
      *(short8v*)(Bh + row*48 + c16*8) = *(const short8v*)(wBh + (size_t)row*768 + k0 + c16*8);
      *(short8v*)(Bl + row*48 + c16*8) = *(const short8v*)(wBl + (size_t)row*768 + k0 + c16*8);
    }
    __syncthreads();

    bf16x8 a_h[4], a_l[4], b_h[4], b_l[4];
    #pragma unroll
    for(int i=0;i<4;i++){
      int ar = wm + i*16 + l16;
      a_h[i] = *(const bf16x8*)(Ah + ar*40 + quad*8);
      a_l[i] = *(const bf16x8*)(Al + ar*40 + quad*8);
      int br = wn + i*16 + l16;
      b_h[i] = *(const bf16x8*)(Bh + br*48 + quad*8);
      b_l[i] = *(const bf16x8*)(Bl + br*48 + quad*8);
    }
    #pragma unroll
    for(int i=0;i<4;i++)
      #pragma unroll
      for(int j=0;j<4;j++){
        acc[i][j] = __builtin_amdgcn_mfma_f32_16x16x32_bf16(a_h[i], b_h[j], acc[i][j],0,0,0);
        acc[i][j] = __builtin_amdgcn_mfma_f32_16x16x32_bf16(a_l[i], b_h[j], acc[i][j],0,0,0);
        acc[i][j] = __builtin_amdgcn_mfma_f32_16x16x32_bf16(a_h[i], b_l[j], acc[i][j],0,0,0);
      }
  }
  // epilogue: D row=(quad*4+r), col=l16
  const size_t cbase = (size_t)(bm*128)*768 + (size_t)bn*128;
  #pragma unroll
  for(int i=0;i<4;i++)
    #pragma unroll
    for(int j=0;j<4;j++)
      #pragma unroll
      for(int r=0;r<4;r++)
        kout[cbase + (size_t)(wm + i*16 + quad*4 + r)*768 + wn + j*16 + l16] = acc[i][j][r];
}

// ---------------------------------------------------------------------------
// Flash-style Hopfield attention: one block per (b,h), 3 iterations in-kernel.
// softmax_1 == softmax with phantom element (logit 0, value 0): init m=0,l=1.
// sT = k . (q*scale)^T via MFMA (A=k-tile from knd, B=q frags);
// PV: acc += P.k via MFMA (A=P from LDS fp32->hi/lo, B=k from kdn transposed).
// All MFMA inputs split-bf16 (3 terms).
// ---------------------------------------------------------------------------
__global__ __launch_bounds__(256, 1)
void attn_kernel(const float* __restrict__ kbuf, const float* __restrict__ q0,
                 float* __restrict__ qout){
  __shared__ float q_s[16*68];                    // q, stride 68 floats
  __shared__ float p_s[16*68];                    // P tile fp32, stride 68
  __shared__ unsigned short knd_h[64*72];         // k[n][d], stride 72 shorts
  __shared__ unsigned short knd_l[64*72];
  __shared__ unsigned short kdn_h[64*68];         // k[d][n], stride 68 shorts
  __shared__ unsigned short kdn_l[64*68];
  __shared__ float m_s[16], lsum_s[16], alpha_s[16];
  __shared__ float wmax[4][16], wsum[4][16];

  const int tid  = threadIdx.x;
  const int bh   = blockIdx.x;
  const int b    = bh / 12;
  const int h    = bh - b*12;
  const int wave = tid >> 6, lane = tid & 63, quad = lane >> 4, l16 = lane & 15;

  const float* kb = kbuf + (size_t)b*4096*768 + h*64;

  // init q_s from q0 (batch-independent learned queries)
  for(int idx = tid; idx < 1024; idx += 256){
    int l = idx >> 6, d = idx & 63;
    q_s[l*68 + d] = q0[l*768 + h*64 + d];
  }
  __syncthreads();

  for(int iter = 0; iter < 3; ++iter){
    if(tid < 16){ m_s[tid] = 0.f; lsum_s[tid] = 1.f; }
    // q B-frags (scale 0.125 folded in): lane holds q[l16][32*s + quad*8 + e]
    bf16x8 qh[2], ql[2];
    #pragma unroll
    for(int s = 0; s < 2; ++s){
      const float* qp = q_s + l16*68 + s*32 + quad*8;
      float4v v0 = *(const float4v*)qp;
      float4v v1 = *(const float4v*)(qp + 4);
      #pragma unroll
      for(int e = 0; e < 8; ++e){
        float v = (e < 4 ? v0[e] : v1[e-4]) * 0.125f;
        unsigned short hh = f2bf_hi(v);
        qh[s][e] = (short)hh;
        ql[s][e] = (short)f2bf_hi(v - bf2f(hh));
      }
    }
    float4v acc = (float4v){0.f,0.f,0.f,0.f};
    __syncthreads();

    for(int t = 0; t < 64; ++t){
      const int n0 = t*64;
      // ---- stage k tile (64 n-rows x 64 d), both layouts, hi/lo ----
      {
        const int d = lane;              // lane-per-d: coalesced 256B loads
        unsigned short hb[16], lb[16];
        #pragma unroll
        for(int i = 0; i < 16; ++i){
          const int nn = wave*16 + i;
          float v = kb[(size_t)(n0+nn)*768 + d];
          unsigned short hh = f2bf_hi(v);
          unsigned short ll = f2bf_hi(v - bf2f(hh));
          hb[i] = hh; lb[i] = ll;
          unsigned ph = (unsigned)__shfl_xor((int)hh, 1);
          unsigned pl = (unsigned)__shfl_xor((int)ll, 1);
          if((d & 1) == 0){
            *((unsigned*)knd_h + nn*36 + (d>>1)) = (unsigned)hh | (ph << 16);
          } else {
            *((unsigned*)knd_l + nn*36 + (d>>1)) = (pl & 0xffffu) | (((unsigned)ll) << 16);
          }
        }
        #pragma unroll
        for(int c = 0; c < 4; ++c){      // thread owns 16 consecutive n at fixed d
          short4v sh, sl;
          #pragma unroll
          for(int e = 0; e < 4; ++e){ sh[e] = (short)hb[c*4+e]; sl[e] = (short)lb[c*4+e]; }
          *(short4v*)(kdn_h + d*68 + wave*16 + c*4) = sh;
          *(short4v*)(kdn_l + d*68 + wave*16 + c*4) = sl;
        }
      }
      __syncthreads();                                   // S1

      // ---- QK^T (transposed): sT[n'][l], wave w owns n' in [16w,16w+16) ----
      bf16x8 ka_h[2], ka_l[2];
      {
        const int nn = wave*16 + l16;
        #pragma unroll
        for(int s = 0; s < 2; ++s){
          ka_h[s] = *(const bf16x8*)(knd_h + nn*72 + s*32 + quad*8);
          ka_l[s] = *(const bf16x8*)(knd_l + nn*72 + s*32 + quad*8);
        }
      }
      float4v sfr = (float4v){0.f,0.f,0.f,0.f};
      #pragma unroll
      for(int s = 0; s < 2; ++s){
        sfr = __builtin_amdgcn_mfma_f32_16x16x32_bf16(ka_h[s], qh[s], sfr, 0,0,0);
        sfr = __builtin_amdgcn_mfma_f32_16x16x32_bf16(ka_l[s], qh[s], sfr, 0,0,0);
        sfr = __builtin_amdgcn_mfma_f32_16x16x32_bf16(ka_h[s], ql[s], sfr, 0,0,0);
      }
      // sfr[r]: logit( l=l16, n = n0 + wave*16 + quad*4 + r )

      float mx = fmaxf(fmaxf(sfr[0], sfr[1]), fmaxf(sfr[2], sfr[3]));
      mx = fmaxf(mx, __shfl_xor(mx, 16));
      mx = fmaxf(mx, __shfl_xor(mx, 32));
      if(quad == 0) wmax[wave][l16] = mx;
      __syncthreads();                                   // S2

      const float m_old = m_s[l16];
      float tm = fmaxf(fmaxf(wmax[0][l16], wmax[1][l16]),
                       fmaxf(wmax[2][l16], wmax[3][l16]));
      const float m_new = fmaxf(m_old, tm);
      const float alpha = __expf(m_old - m_new);
      float4v p;
      #pragma unroll
      for(int r = 0; r < 4; ++r) p[r] = __expf(sfr[r] - m_new);
      *(float4v*)(p_s + l16*68 + wave*16 + quad*4) = p;
      float ssum = p[0]+p[1]+p[2]+p[3];
      ssum += __shfl_xor(ssum, 16);
      ssum += __shfl_xor(ssum, 32);
      if(quad == 0) wsum[wave][l16] = ssum;
      if(tid < 16) alpha_s[tid] = alpha;
      __syncthreads();                                   // S3

      if(tid < 16){
        float ts = wsum[0][tid] + wsum[1][tid] + wsum[2][tid] + wsum[3][tid];
        lsum_s[tid] = lsum_s[tid]*alpha + ts;
        m_s[tid] = m_new;
      }
      // rescale acc rows by alpha, then PV accumulate
      {
        #pragma unroll
        for(int r = 0; r < 4; ++r) acc[r] *= alpha_s[quad*4 + r];
      }
      #pragma unroll
      for(int s = 0; s < 2; ++s){
        const float* pp = p_s + l16*68 + s*32 + quad*8;
        float4v p0 = *(const float4v*)pp;
        float4v p1 = *(const float4v*)(pp + 4);
        bf16x8 pa_h, pa_l;
        #pragma unroll
        for(int e = 0; e < 8; ++e){
          float v = (e < 4 ? p0[e] : p1[e-4]);
          unsigned short hh = f2bf_hi(v);
          pa_h[e] = (short)hh;
          pa_l[e] = (short)f2bf_hi(v - bf2f(hh));
        }
        const unsigned short* bp_h = kdn_h + (wave*16 + l16)*68 + s*32 + quad*8;
        const unsigned short* bp_l = kdn_l + (wave*16 + l16)*68 + s*32 + quad*8;
        short4v h0 = *(const short4v*)bp_h, h1 = *(const short4v*)(bp_h + 4);
        short4v l0 = *(const short4v*)bp_l, l1 = *(const short4v*)(bp_l + 4);
        bf16x8 kb_h = (bf16x8){h0[0],h0[1],h0[2],h0[3],h1[0],h1[1],h1[2],h1[3]};
        bf16x8 kb_l = (bf16x8){l0[0],l0[1],l0[2],l0[3],l1[0],l1[1],l1[2],l1[3]};
        acc = __builtin_amdgcn_mfma_f32_16x16x32_bf16(pa_h, kb_h, acc, 0,0,0);
        acc = __builtin_amdgcn_mfma_f32_16x16x32_bf16(pa_l, kb_h, acc, 0,0,0);
        acc = __builtin_amdgcn_mfma_f32_16x16x32_bf16(pa_h, kb_l, acc, 0,0,0);
      }
      __syncthreads();                                   // S4
    } // tiles

    // finalize: q_new = acc / lsum ; acc[r] -> (l=quad*4+r, d=wave*16+l16)
    #pragma unroll
    for(int r = 0; r < 4; ++r){
      const int l = quad*4 + r;
      const float qv = acc[r] / lsum_s[l];
      if(iter < 2){
        q_s[l*68 + wave*16 + l16] = qv;
      } else {
        qout[(size_t)(b*16 + l)*768 + h*64 + wave*16 + l16] = qv;
      }
    }
    __syncthreads();                                     // S5
  }
}

// ---------------------------------------------------------------------------
// out[r][c] = sum_j inp[r][j]*W[c][j] (+bias). 4 rows per block, fp32.
// ---------------------------------------------------------------------------
__global__ __launch_bounds__(256)
void proj_kernel(const float* __restrict__ inp, const float* __restrict__ w,
                 const float* __restrict__ bias, float* __restrict__ out){
  __shared__ float rows[4*768];
  const int r0 = blockIdx.x*4;
  for(int j = threadIdx.x; j < 4*768; j += 256) rows[j] = inp[(size_t)r0*768 + j];
  __syncthreads();
  #pragma unroll
  for(int cc = 0; cc < 3; ++cc){
    const int c = cc*256 + threadIdx.x;
    const float* wr = w + (size_t)c*768;
    float a0=0.f, a1=0.f, a2=0.f, a3=0.f;
    for(int j=0;j<768;j+=4){
      float4v w4 = *(const float4v*)(wr+j);
      float4v r0v = *(const float4v*)(rows+j);
      float4v r1v = *(const float4v*)(rows+768+j);
      float4v r2v = *(const float4v*)(rows+1536+j);
      float4v r3v = *(const float4v*)(rows+2304+j);
      #pragma unroll
      for(int e=0;e<4;e++){
        a0 += r0v[e]*w4[e]; a1 += r1v[e]*w4[e];
        a2 += r2v[e]*w4[e]; a3 += r3v[e]*w4[e];
      }
    }
    const float bb = bias ? bias[c] : 0.f;
    out[(size_t)(r0+0)*768 + c] = a0 + bb;
    out[(size_t)(r0+1)*768 + c] = a1 + bb;
    out[(size_t)(r0+2)*768 + c] = a2 + bb;
    out[(size_t)(r0+3)*768 + c] = a3 + bb;
  }
}

// ---------------------------------------------------------------------------
extern "C" void kernel_launch(void* const* d_in, const int* in_sizes, int n_in,
                              void* d_out, int out_size, void* d_ws, size_t ws_size,
                              hipStream_t stream){
  const float* x     = (const float*)d_in[0];   // [16,4096,768]
  const float* query = (const float*)d_in[1];   // [1,16,768]
  const float* Wq    = (const float*)d_in[2];   // [768,768]
  const float* Wk    = (const float*)d_in[3];
  const float* Wv    = (const float*)d_in[4];
  const float* Wproj = (const float*)d_in[5];
  const float* bproj = (const float*)d_in[6];   // [768]
  float* out = (float*)d_out;                   // [16,16,768] fp32

  char* ws = (char*)d_ws;
  // workspace layout (~205.3 MB total)
  float*          kbuf = (float*)(ws);                                   // 201326592 B
  unsigned short* wkh  = (unsigned short*)(ws + 201326592);              // 1179648 B
  unsigned short* wkl  = (unsigned short*)(ws + 201326592 + 1179648);    // 1179648 B
  float*          q0   = (float*)(ws + 201326592 + 2*1179648);           // 49152 B
  float*          qout = (float*)(ws + 201326592 + 2*1179648 + 49152);   // 786432 B
  float*          out1 = (float*)(ws + 201326592 + 2*1179648 + 49152 + 786432);

  cvt_w_kernel<<<576, 256, 0, stream>>>(Wk, wkh, wkl);
  q0_kernel<<<48, 256, 0, stream>>>(query, Wq, q0);
  gemm_k_kernel<<<dim3(512, 6), 256, 0, stream>>>(x, wkh, wkl, kbuf);
  attn_kernel<<<192, 256, 0, stream>>>(kbuf, q0, qout);
  proj_kernel<<<64, 256, 0, stream>>>(qout, Wv, nullptr, out1);
  proj_kernel<<<64, 256, 0, stream>>>(out1, Wproj, bproj, out);
}

// Round 2
// 760.561 us; speedup vs baseline: 2.8280x; 2.8280x over previous
//
#include <hip/hip_runtime.h>

// ---------------------------------------------------------------------------
// HopfieldPooling on MI355X (gfx950)
//   k = x@Wk^T  (split-bf16 MFMA GEMM, 3-term)
//   q0 = query@Wq^T (fp32)
//   3x Hopfield steps: split-N flash attention WITHOUT online max
//     (softmax_1 = exp(a)/(1+sum exp(a)), logits bounded -> fixed shift m=0)
//     partials combined via fp32 atomicAdd + normalize kernel between steps
//   out = (q@Wv^T)@Wproj^T + b  (fp32 vector)
// ---------------------------------------------------------------------------

typedef float  float4v  __attribute__((ext_vector_type(4)));
typedef short  short4v  __attribute__((ext_vector_type(4)));
typedef short  short8v  __attribute__((ext_vector_type(8)));
typedef unsigned int uint4v __attribute__((ext_vector_type(4)));
typedef short8v bf16x8;   // 8 bf16 = 4 VGPRs, MFMA A/B frag

#define NC 8   // n-chunks per (b,h) in attention step

__device__ __forceinline__ unsigned short f2bf_hi(float f){
  unsigned int u = __float_as_uint(f);
  u += 0x7fffu + ((u >> 16) & 1u);            // round-to-nearest-even
  return (unsigned short)(u >> 16);
}
__device__ __forceinline__ float bf2f(unsigned short h){
  return __uint_as_float(((unsigned int)h) << 16);
}

// ---------------------------------------------------------------------------
// Wk -> hi/lo bf16 preconversion (768x768)
// ---------------------------------------------------------------------------
__global__ __launch_bounds__(256)
void cvt_w_kernel(const float* __restrict__ w, unsigned short* __restrict__ wh,
                  unsigned short* __restrict__ wl){
  int idx = blockIdx.x*256 + threadIdx.x;     // 147456 float4s
  float4v v = ((const float4v*)w)[idx];
  short4v h4, l4;
  #pragma unroll
  for(int e=0;e<4;e++){
    unsigned short hh = f2bf_hi(v[e]);
    h4[e] = (short)hh;
    l4[e] = (short)f2bf_hi(v[e] - bf2f(hh));
  }
  ((short4v*)wh)[idx] = h4;
  ((short4v*)wl)[idx] = l4;
}

// ---------------------------------------------------------------------------
// q0[l][c] = sum_j query[l][j]*Wq[c][j]   (16x768, fp32)
// ---------------------------------------------------------------------------
__global__ __launch_bounds__(256)
void q0_kernel(const float* __restrict__ query, const float* __restrict__ wq,
               float* __restrict__ q0){
  int idx = blockIdx.x*256 + threadIdx.x;     // 12288
  int l = idx / 768, c = idx - l*768;
  const float* qr = query + l*768;
  const float* wr = wq + (size_t)c*768;
  float s = 0.f;
  for(int j=0;j<768;j+=4){
    float4v a  = *(const float4v*)(qr+j);
    float4v w4 = *(const float4v*)(wr+j);
    s += a[0]*w4[0]+a[1]*w4[1]+a[2]*w4[2]+a[3]*w4[3];
  }
  q0[idx] = s;
}

// ---------------------------------------------------------------------------
// k = x @ Wk^T : M=65536, N=768, K=768. 128x128 tile, BK=32, 4 waves. fp32 out.
// ---------------------------------------------------------------------------
__global__ __launch_bounds__(256, 2)
void gemm_k_kernel(const float* __restrict__ x, const unsigned short* __restrict__ wh,
                   const unsigned short* __restrict__ wl, float* __restrict__ kout){
  __shared__ unsigned short Ah[128*40], Al[128*40];   // stride 40 shorts (pad)
  __shared__ unsigned short Bh[128*48], Bl[128*48];   // stride 48 shorts (pad)
  const int tid  = threadIdx.x;
  const int bm   = blockIdx.x;   // 0..511
  const int bn   = blockIdx.y;   // 0..5
  const int wave = tid >> 6, lane = tid & 63, quad = lane >> 4, l16 = lane & 15;
  const int wm   = (wave >> 1)*64, wn = (wave & 1)*64;

  float4v acc[4][4];
  #pragma unroll
  for(int i=0;i<4;i++)
    #pragma unroll
    for(int j=0;j<4;j++) acc[i][j] = (float4v){0.f,0.f,0.f,0.f};

  const float* xA = x + (size_t)bm*128*768;
  const unsigned short* wBh = wh + (size_t)bn*128*768;
  const unsigned short* wBl = wl + (size_t)bn*128*768;

  for(int k0=0;k0<768;k0+=32){
    __syncthreads();
    #pragma unroll
    for(int i=0;i<4;i++){
      int fi = tid + i*256;          // 0..1023
      int row = fi >> 3, c4 = fi & 7;
      float4v va = *(const float4v*)(xA + (size_t)row*768 + k0 + c4*4);
      short4v ha, la;
      #pragma unroll
      for(int e=0;e<4;e++){
        unsigned short hh = f2bf_hi(va[e]);
        ha[e] = (short)hh;
        la[e] = (short)f2bf_hi(va[e] - bf2f(hh));
      }
      *(short4v*)(Ah + row*40 + c4*4) = ha;
      *(short4v*)(Al + row*40 + c4*4) = la;
    }
    #pragma unroll
    for(int i=0;i<2;i++){
      int ci = tid + i*256;          // 0..511
      int row = ci >> 2, c16 = ci & 3;
      *(short8v*)(Bh + row*48 + c16*8) = *(const short8v*)(wBh + (size_t)row*768 + k0 + c16*8);
      *(short8v*)(Bl + row*48 + c16*8) = *(const short8v*)(wBl + (size_t)row*768 + k0 + c16*8);
    }
    __syncthreads();

    bf16x8 a_h[4], a_l[4], b_h[4], b_l[4];
    #pragma unroll
    for(int i=0;i<4;i++){
      int ar = wm + i*16 + l16;
      a_h[i] = *(const bf16x8*)(Ah + ar*40 + quad*8);
      a_l[i] = *(const bf16x8*)(Al + ar*40 + quad*8);
      int br = wn + i*16 + l16;
      b_h[i] = *(const bf16x8*)(Bh + br*48 + quad*8);
      b_l[i] = *(const bf16x8*)(Bl + br*48 + quad*8);
    }
    #pragma unroll
    for(int i=0;i<4;i++)
      #pragma unroll
      for(int j=0;j<4;j++){
        acc[i][j] = __builtin_amdgcn_mfma_f32_16x16x32_bf16(a_h[i], b_h[j], acc[i][j],0,0,0);
        acc[i][j] = __builtin_amdgcn_mfma_f32_16x16x32_bf16(a_l[i], b_h[j], acc[i][j],0,0,0);
        acc[i][j] = __builtin_amdgcn_mfma_f32_16x16x32_bf16(a_h[i], b_l[j], acc[i][j],0,0,0);
      }
  }
  const size_t cbase = (size_t)(bm*128)*768 + (size_t)bn*128;
  #pragma unroll
  for(int i=0;i<4;i++)
    #pragma unroll
    for(int j=0;j<4;j++)
      #pragma unroll
      for(int r=0;r<4;r++)
        kout[cbase + (size_t)(wm + i*16 + quad*4 + r)*768 + wn + j*16 + l16] = acc[i][j][r];
}

// ---------------------------------------------------------------------------
// Attention step: one Hopfield iteration, split over NC n-chunks.
// Block = (chunk c, head h, batch b), 512 n-rows per block (8 tiles of 64).
// No online max (fixed shift 0). Unnormalized partials -> atomicAdd.
// LDS holds k tile packed (hi | lo<<16) in both [n][d] and [d][n] layouts.
// ---------------------------------------------------------------------------
__global__ __launch_bounds__(256, 4)
void attn_step_kernel(const float* __restrict__ kbuf, const float* __restrict__ qsrc,
                      long qb_stride, float* __restrict__ qacc, float* __restrict__ lacc){
  __shared__ unsigned int knd[64*68];   // packed, [n][d], stride 68 words
  __shared__ unsigned int kdn[64*65];   // packed, [d][n], stride 65 words
  __shared__ float p_s[16*68];          // P tile fp32, stride 68
  __shared__ float red[4][16];

  const int tid  = threadIdx.x;
  const int c    = blockIdx.x;          // 0..NC-1
  const int h    = blockIdx.y;          // 0..11
  const int b    = blockIdx.z;          // 0..15
  const int wave = tid >> 6, lane = tid & 63, quad = lane >> 4, l16 = lane & 15;

  const float* kb = kbuf + ((size_t)b*4096 + (size_t)c*(4096/NC))*768 + h*64;

  // q fragments (scale 1/8 folded), split hi/lo. lane l16 = l.
  const float* qp = qsrc + (size_t)b*qb_stride + (size_t)l16*768 + h*64;
  bf16x8 qh[2], ql[2];
  #pragma unroll
  for(int s = 0; s < 2; ++s){
    float4v v0 = *(const float4v*)(qp + s*32 + quad*8);
    float4v v1 = *(const float4v*)(qp + s*32 + quad*8 + 4);
    #pragma unroll
    for(int e = 0; e < 8; ++e){
      float v = (e < 4 ? v0[e] : v1[e-4]) * 0.125f;
      unsigned short hh = f2bf_hi(v);
      qh[s][e] = (short)hh;
      ql[s][e] = (short)f2bf_hi(v - bf2f(hh));
    }
  }

  float4v acc = (float4v){0.f,0.f,0.f,0.f};
  float lsum = 0.f;

  const int sn = tid >> 2;   // staging: tile row 0..63
  const int dq = tid & 3;    // staging: 16-d group

  for(int t = 0; t < (4096/NC)/64; ++t){
    // ---- stage 64x64 k tile: fp32 -> packed (hi | lo<<16), both layouts ----
    const float* src = kb + (size_t)(t*64 + sn)*768 + dq*16;
    #pragma unroll
    for(int g = 0; g < 4; ++g){
      float4v va = *(const float4v*)(src + g*4);
      unsigned int pk0, pk1, pk2, pk3;
      {
        unsigned short hh0 = f2bf_hi(va[0]); pk0 = (unsigned)hh0 | ((unsigned)f2bf_hi(va[0]-bf2f(hh0)) << 16);
        unsigned short hh1 = f2bf_hi(va[1]); pk1 = (unsigned)hh1 | ((unsigned)f2bf_hi(va[1]-bf2f(hh1)) << 16);
        unsigned short hh2 = f2bf_hi(va[2]); pk2 = (unsigned)hh2 | ((unsigned)f2bf_hi(va[2]-bf2f(hh2)) << 16);
        unsigned short hh3 = f2bf_hi(va[3]); pk3 = (unsigned)hh3 | ((unsigned)f2bf_hi(va[3]-bf2f(hh3)) << 16);
      }
      *(uint4v*)(knd + sn*68 + dq*16 + g*4) = (uint4v){pk0, pk1, pk2, pk3};
      const int dbase = dq*16 + g*4;
      kdn[(dbase+0)*65 + sn] = pk0;
      kdn[(dbase+1)*65 + sn] = pk1;
      kdn[(dbase+2)*65 + sn] = pk2;
      kdn[(dbase+3)*65 + sn] = pk3;
    }
    __syncthreads();                                   // S1: tile staged

    // ---- QK^T transposed: sT[n'][l]; wave w owns n' in [16w, 16w+16) ----
    float4v sfr = (float4v){0.f,0.f,0.f,0.f};
    #pragma unroll
    for(int s = 0; s < 2; ++s){
      const unsigned int* ap = knd + (wave*16 + l16)*68 + s*32 + quad*8;
      uint4v w0 = *(const uint4v*)ap;
      uint4v w1 = *(const uint4v*)(ap + 4);
      bf16x8 a_h, a_l;
      #pragma unroll
      for(int j = 0; j < 4; ++j){
        a_h[j]   = (short)(w0[j] & 0xffffu);  a_l[j]   = (short)(w0[j] >> 16);
        a_h[j+4] = (short)(w1[j] & 0xffffu);  a_l[j+4] = (short)(w1[j] >> 16);
      }
      sfr = __builtin_amdgcn_mfma_f32_16x16x32_bf16(a_h, qh[s], sfr, 0,0,0);
      sfr = __builtin_amdgcn_mfma_f32_16x16x32_bf16(a_l, qh[s], sfr, 0,0,0);
      sfr = __builtin_amdgcn_mfma_f32_16x16x32_bf16(a_h, ql[s], sfr, 0,0,0);
    }
    // sfr[r]: logit(l=l16, n_local = wave*16 + quad*4 + r)
    float4v p;
    #pragma unroll
    for(int r = 0; r < 4; ++r) p[r] = __expf(sfr[r]);
    lsum += p[0] + p[1] + p[2] + p[3];
    *(float4v*)(p_s + l16*68 + wave*16 + quad*4) = p;
    __syncthreads();                                   // S2: p_s ready

    // ---- PV: acc[l][d] += P[l][n] k[n][d]; wave w owns d in [16w,16w+16) ----
    #pragma unroll
    for(int s = 0; s < 2; ++s){
      const float* pp = p_s + l16*68 + s*32 + quad*8;
      float4v p0 = *(const float4v*)pp;
      float4v p1 = *(const float4v*)(pp + 4);
      bf16x8 pa_h, pa_l;
      #pragma unroll
      for(int e = 0; e < 8; ++e){
        float v = (e < 4 ? p0[e] : p1[e-4]);
        unsigned short hh = f2bf_hi(v);
        pa_h[e] = (short)hh;
        pa_l[e] = (short)f2bf_hi(v - bf2f(hh));
      }
      const unsigned int* bp = kdn + (wave*16 + l16)*65 + s*32 + quad*8;
      bf16x8 kb_h, kb_l;
      #pragma unroll
      for(int j = 0; j < 8; ++j){
        unsigned int w = bp[j];
        kb_h[j] = (short)(w & 0xffffu);
        kb_l[j] = (short)(w >> 16);
      }
      acc = __builtin_amdgcn_mfma_f32_16x16x32_bf16(pa_h, kb_h, acc, 0,0,0);
      acc = __builtin_amdgcn_mfma_f32_16x16x32_bf16(pa_l, kb_h, acc, 0,0,0);
      acc = __builtin_amdgcn_mfma_f32_16x16x32_bf16(pa_h, kb_l, acc, 0,0,0);
    }
    __syncthreads();                                   // S3: done with tile LDS
  }

  // ---- epilogue: reduce lsum per l, atomic partials ----
  lsum += __shfl_xor(lsum, 16);
  lsum += __shfl_xor(lsum, 32);
  if(quad == 0) red[wave][l16] = lsum;
  __syncthreads();
  if(tid < 16){
    float tot = red[0][tid] + red[1][tid] + red[2][tid] + red[3][tid];
    atomicAdd(&lacc[(b*12 + h)*16 + tid], tot);
  }
  #pragma unroll
  for(int r = 0; r < 4; ++r){
    atomicAdd(&qacc[(size_t)(b*16 + quad*4 + r)*768 + h*64 + wave*16 + l16], acc[r]);
  }
}

// ---------------------------------------------------------------------------
// Normalize: qcur = qacc / (1 + lacc); then zero qacc/lacc for the next step.
// ---------------------------------------------------------------------------
__global__ __launch_bounds__(256)
void attn_norm_kernel(float* __restrict__ qacc, float* __restrict__ lacc,
                      float* __restrict__ qcur){
  __shared__ float lt[16];
  const int bh = blockIdx.x, b = bh/12, h = bh - (bh/12)*12, tid = threadIdx.x;
  if(tid < 16) lt[tid] = 1.f + lacc[bh*16 + tid];
  __syncthreads();
  if(tid < 16) lacc[bh*16 + tid] = 0.f;
  for(int idx = tid; idx < 1024; idx += 256){
    int l = idx >> 6, d = idx & 63;
    size_t a = (size_t)(b*16 + l)*768 + h*64 + d;
    qcur[a] = qacc[a] / lt[l];
    qacc[a] = 0.f;
  }
}

// ---------------------------------------------------------------------------
// out[r][c] = sum_j inp[r][j]*W[c][j] (+bias). 4 rows x 256 cols per block.
// ---------------------------------------------------------------------------
__global__ __launch_bounds__(256)
void proj_kernel(const float* __restrict__ inp, const float* __restrict__ w,
                 const float* __restrict__ bias, float* __restrict__ out){
  __shared__ float rows[4*768];
  const int r0 = blockIdx.x*4;
  const int c  = blockIdx.y*256 + threadIdx.x;
  for(int j = threadIdx.x; j < 4*768; j += 256) rows[j] = inp[(size_t)r0*768 + j];
  __syncthreads();
  const float* wr = w + (size_t)c*768;
  float a0=0.f, a1=0.f, a2=0.f, a3=0.f;
  for(int j=0;j<768;j+=4){
    float4v w4 = *(const float4v*)(wr+j);
    float4v r0v = *(const float4v*)(rows+j);
    float4v r1v = *(const float4v*)(rows+768+j);
    float4v r2v = *(const float4v*)(rows+1536+j);
    float4v r3v = *(const float4v*)(rows+2304+j);
    #pragma unroll
    for(int e=0;e<4;e++){
      a0 += r0v[e]*w4[e]; a1 += r1v[e]*w4[e];
      a2 += r2v[e]*w4[e]; a3 += r3v[e]*w4[e];
    }
  }
  const float bb = bias ? bias[c] : 0.f;
  out[(size_t)(r0+0)*768 + c] = a0 + bb;
  out[(size_t)(r0+1)*768 + c] = a1 + bb;
  out[(size_t)(r0+2)*768 + c] = a2 + bb;
  out[(size_t)(r0+3)*768 + c] = a3 + bb;
}

// ---------------------------------------------------------------------------
extern "C" void kernel_launch(void* const* d_in, const int* in_sizes, int n_in,
                              void* d_out, int out_size, void* d_ws, size_t ws_size,
                              hipStream_t stream){
  const float* x     = (const float*)d_in[0];   // [16,4096,768]
  const float* query = (const float*)d_in[1];   // [1,16,768]
  const float* Wq    = (const float*)d_in[2];   // [768,768]
  const float* Wk    = (const float*)d_in[3];
  const float* Wv    = (const float*)d_in[4];
  const float* Wproj = (const float*)d_in[5];
  const float* bproj = (const float*)d_in[6];   // [768]
  float* out = (float*)d_out;                   // [16,16,768] fp32

  char* ws = (char*)d_ws;
  // layout (204.5 MB total; wk region reused as qacc/lacc, then out1)
  float*          kbuf = (float*)(ws);                       // 201326592 B
  float*          qcur = (float*)(ws + 201326592);           // 786432 B
  float*          q0   = (float*)(ws + 202113024);           // 49152 B
  char*           R    = ws + 202162176;                     // 2359296 B region
  unsigned short* wkh  = (unsigned short*)(R);               // gemm phase
  unsigned short* wkl  = (unsigned short*)(R + 1179648);
  float*          qacc = (float*)(R);                        // attn phase (alias)
  float*          lacc = (float*)(R + 786432);               // 12288 B
  float*          out1 = (float*)(R);                        // proj phase (alias)

  cvt_w_kernel<<<576, 256, 0, stream>>>(Wk, wkh, wkl);
  q0_kernel<<<48, 256, 0, stream>>>(query, Wq, q0);
  gemm_k_kernel<<<dim3(512, 6), 256, 0, stream>>>(x, wkh, wkl, kbuf);

  hipMemsetAsync(qacc, 0, 786432 + 12288, stream);
  dim3 sg(NC, 12, 16);
  attn_step_kernel<<<sg, 256, 0, stream>>>(kbuf, q0,   0,       qacc, lacc);
  attn_norm_kernel<<<192, 256, 0, stream>>>(qacc, lacc, qcur);
  attn_step_kernel<<<sg, 256, 0, stream>>>(kbuf, qcur, 16*768,  qacc, lacc);
  attn_norm_kernel<<<192, 256, 0, stream>>>(qacc, lacc, qcur);
  attn_step_kernel<<<sg, 256, 0, stream>>>(kbuf, qcur, 16*768,  qacc, lacc);
  attn_norm_kernel<<<192, 256, 0, stream>>>(qacc, lacc, qcur);

  proj_kernel<<<dim3(64, 3), 256, 0, stream>>>(qcur, Wv, nullptr, out1);
  proj_kernel<<<dim3(64, 3), 256, 0, stream>>>(out1, Wproj, bproj, out);
}